// Round 23
// baseline (2547.770 us; speedup 1.0000x reference)
//
#include <hip/hip_runtime.h>
#include <math.h>

#define NN 100000
#define NE 1600000
#define DD 64
#define NL 4
#define NH 4
#define NC 16
#define DIN 192
#define SLOPE 0.2f
#define EB 64
#define XSTR 200
#define FSTR 66
#define RSTR 68
#define LOG2E 1.44269504088896340736f

typedef __bf16 bf8 __attribute__((ext_vector_type(8)));
typedef __bf16 bf4 __attribute__((ext_vector_type(4)));
typedef __bf16 bf2 __attribute__((ext_vector_type(2)));
typedef float f32x4 __attribute__((ext_vector_type(4)));

__device__ __forceinline__ f32x4 MFMA(bf8 a, bf8 b, f32x4 c) {
  return __builtin_amdgcn_mfma_f32_16x16x32_bf16(a, b, c, 0, 0, 0);
}

// ---------------- weight packing: single bf16 plane, 1KB tiles ----------------
__global__ void k_pack_w1(const float* __restrict__ W1, __bf16* __restrict__ WH) {
  int gidx = blockIdx.x * 256 + threadIdx.x;
  if (gidx >= 4 * 4608) return;
  int lyr = gidx / 4608, rem = gidx % 4608;
  int lane = rem & 63, ts = rem >> 6;
  int s = ts % 6, t = ts / 6;
  const float* Wl = W1 + (size_t)lyr * DIN * DIN;
  size_t base = (size_t)lyr * 36864 + ((size_t)(t * 6 + s) * 64 + lane) * 8;
  int k0 = s * 32 + (lane >> 4) * 8, n = t * 16 + (lane & 15);
#pragma unroll
  for (int j = 0; j < 8; ++j)
    WH[base + j] = (__bf16)Wl[(size_t)(k0 + j) * DIN + n];
}

__global__ void k_pack_w2(const float* __restrict__ W2, __bf16* __restrict__ WH) {
  int gidx = blockIdx.x * 256 + threadIdx.x;
  if (gidx >= 4 * 1536) return;
  int lyr = gidx / 1536, rem = gidx % 1536;
  int lane = rem & 63, ts = rem >> 6;
  int s = ts % 6, t = ts / 6;
  const float* Wl = W2 + (size_t)lyr * DIN * DD;
  size_t base = (size_t)lyr * 12288 + ((size_t)(t * 6 + s) * 64 + lane) * 8;
  int k0 = s * 32 + (lane >> 4) * 8, n = t * 16 + (lane & 15);
#pragma unroll
  for (int j = 0; j < 8; ++j)
    WH[base + j] = (__bf16)Wl[(size_t)(k0 + j) * DD + n];
}

// W2VP[l] = W2_l @ v_{l+1}; VP[l] = v_{l+1}; bvdot[l][h] = b2_l . v_{l+1}[:,h]
__global__ void k_w2v(const float* __restrict__ up2_w, const float* __restrict__ up2_b,
                      const float* __restrict__ vbuf, __bf16* __restrict__ W2VP,
                      __bf16* __restrict__ VP, float* __restrict__ bvdot) {
  int l = blockIdx.x;
  const float* vn = vbuf + (l + 1) * 256;
  int t = threadIdx.x;
  if (t < 384) {
    int s = t >> 6, lane = t & 63;
    int i = lane & 15, k0 = s * 32 + (lane >> 4) * 8;
    const float* W2 = up2_w + (size_t)l * DIN * DD;
    __bf16* out = W2VP + (size_t)l * 3072 + ((size_t)(s * 64 + lane)) * 8;
#pragma unroll
    for (int j = 0; j < 8; ++j) {
      float val = 0.f;
      if (i < 4)
        for (int n = 0; n < DD; ++n)
          val = fmaf(W2[(size_t)(k0 + j) * DD + n], vn[n * NH + i], val);
      out[j] = (__bf16)val;
    }
  }
  if (t < 128) {
    int s2 = t >> 6, lane = t & 63;
    int i = lane & 15, k0 = s2 * 32 + (lane >> 4) * 8;
    __bf16* out = VP + (size_t)l * 1024 + ((size_t)(s2 * 64 + lane)) * 8;
#pragma unroll
    for (int j = 0; j < 8; ++j)
      out[j] = (i < 4) ? (__bf16)vn[(k0 + j) * NH + i] : (__bf16)0.f;
  }
  if (t < 4) {
    const float* b2 = up2_b + (size_t)l * DD;
    float bv = 0.f;
    for (int n = 0; n < DD; ++n) bv = fmaf(b2[n], vn[n * NH + t], bv);
    bvdot[l * 4 + t] = bv;
  }
}

// ---------------- CSR build ----------------
__global__ void k_zero(int* __restrict__ deg) {
  int i = blockIdx.x * 256 + threadIdx.x;
  if (i < NN) deg[i] = 0;
}

__global__ void k_hist(const int* __restrict__ dst, int* __restrict__ deg) {
  int e = blockIdx.x * 256 + threadIdx.x;
  if (e < NE) atomicAdd(&deg[dst[e]], 1);
}

__global__ void k_scan1(const int* __restrict__ deg, int* __restrict__ offs,
                        int* __restrict__ bsum) {
  __shared__ int sh[256];
  int t = threadIdx.x, b = blockIdx.x;
  int i0 = b * 1024 + t * 4;
  int d0 = (i0 + 0 < NN) ? deg[i0 + 0] : 0;
  int d1 = (i0 + 1 < NN) ? deg[i0 + 1] : 0;
  int d2 = (i0 + 2 < NN) ? deg[i0 + 2] : 0;
  int d3 = (i0 + 3 < NN) ? deg[i0 + 3] : 0;
  int s4 = d0 + d1 + d2 + d3;
  sh[t] = s4;
  __syncthreads();
  int p = 0;
#pragma unroll
  for (int off = 1; off < 256; off <<= 1) {
    int v = (t >= off) ? sh[t - off] : 0;
    __syncthreads();
    sh[t] += v;
    __syncthreads();
  }
  p = sh[t] - s4;
  if (t == 255) bsum[b] = sh[255];
  if (i0 + 0 < NN) offs[i0 + 0] = p;
  if (i0 + 1 < NN) offs[i0 + 1] = p + d0;
  if (i0 + 2 < NN) offs[i0 + 2] = p + d0 + d1;
  if (i0 + 3 < NN) offs[i0 + 3] = p + d0 + d1 + d2;
}

__global__ void k_scan2(int* __restrict__ bsum, int* __restrict__ boff,
                        int* __restrict__ offs, int nb) {
  if (threadIdx.x == 0 && blockIdx.x == 0) {
    int run = 0;
    for (int k = 0; k < nb; ++k) { boff[k] = run; run += bsum[k]; }
    offs[NN] = NE;
  }
}

__global__ void k_scan3(int* __restrict__ offs, const int* __restrict__ boff,
                        int* __restrict__ cursor) {
  int i = blockIdx.x * 256 + threadIdx.x;
  if (i < NN) {
    int v = offs[i] + boff[i >> 10];
    offs[i] = v;
    cursor[i] = v;
  }
}

// packed CSR: csr_pack[pos] = (src[e], e)
__global__ void k_scatter(const int* __restrict__ src, const int* __restrict__ dst,
                          int* __restrict__ cursor, int2* __restrict__ csr_pack) {
  int e = blockIdx.x * 256 + threadIdx.x;
  if (e >= NE) return;
  int pos = atomicAdd(&cursor[dst[e]], 1);
  csr_pack[pos] = make_int2(src[e], e);
}

// ---------------- upfront precomputes ----------------
__global__ void k_v_all(const float* __restrict__ ew_all, const float* __restrict__ ae_all,
                        float* __restrict__ vbuf) {
  int l = blockIdx.x;
  const float* ew = ew_all + (size_t)l * DD * DD;
  const float* ae = ae_all + (size_t)l * NH * NC;
  int d = threadIdx.x >> 2, h = threadIdx.x & 3;
  float s = 0.f;
#pragma unroll
  for (int c = 0; c < NC; ++c) s = fmaf(ew[d * DD + h * NC + c], ae[h * NC + c], s);
  vbuf[l * 256 + d * NH + h] = s;
}

// layer-0 xh from node_feats; also emits nf16 carry
__global__ void k_xh0(const float* __restrict__ node_feats, const float* __restrict__ W,
                      const float* __restrict__ as_, const float* __restrict__ ad_,
                      __bf16* __restrict__ nf16, __bf16* __restrict__ xh16,
                      float* __restrict__ asrc, float* __restrict__ adst) {
  int t = blockIdx.x * 4 + (threadIdx.x >> 6);
  int d = threadIdx.x & 63;
  if (t >= NN) return;
  const float* x = node_feats + (size_t)t * DD;
  nf16[(size_t)t * DD + d] = (__bf16)x[d];
  float acc = 0.f;
#pragma unroll
  for (int k = 0; k < DD; ++k) acc = fmaf(x[k], W[k * DD + d], acc);
  xh16[(size_t)t * DD + d] = (__bf16)acc;
  int h = d >> 4, c = d & 15;
  float ps = acc * as_[h * NC + c];
  float pd = acc * ad_[h * NC + c];
#pragma unroll
  for (int off = 8; off >= 1; off >>= 1) {
    ps += __shfl_xor(ps, off, 64);
    pd += __shfl_xor(pd, off, 64);
  }
  if (c == 0) { asrc[t * NH + h] = ps; adst[t * NH + h] = pd; }
}

// layer-0: edge_feats -> ef16 + araw[e] = pe + asrc0[src[e]]  (asrc folded in)
__global__ void k_pass1f(const float* __restrict__ edge_feats,
                         const float* __restrict__ v,
                         const int* __restrict__ src, const float* __restrict__ asrc0,
                         __bf16* __restrict__ ef16, float* __restrict__ araw) {
  int e = blockIdx.x * 64 + (threadIdx.x >> 2);
  int part = threadIdx.x & 3;
  if (e >= NE) return;
  float ph0 = 0.f, ph1 = 0.f, ph2 = 0.f, ph3 = 0.f;
  const float4* ep = (const float4*)(edge_feats + (size_t)e * DD + part * 16);
  const float4* v4 = (const float4*)v;
  bf4 outv[4];
#pragma unroll
  for (int c4 = 0; c4 < 4; ++c4) {
    float4 x = ep[c4];
    outv[c4][0] = (__bf16)x.x; outv[c4][1] = (__bf16)x.y;
    outv[c4][2] = (__bf16)x.z; outv[c4][3] = (__bf16)x.w;
    int d0 = part * 16 + c4 * 4;
    float4 va = v4[d0], vb = v4[d0 + 1], vc = v4[d0 + 2], vd = v4[d0 + 3];
    ph0 = fmaf(x.x, va.x, fmaf(x.y, vb.x, fmaf(x.z, vc.x, fmaf(x.w, vd.x, ph0))));
    ph1 = fmaf(x.x, va.y, fmaf(x.y, vb.y, fmaf(x.z, vc.y, fmaf(x.w, vd.y, ph1))));
    ph2 = fmaf(x.x, va.z, fmaf(x.y, vb.z, fmaf(x.z, vc.z, fmaf(x.w, vd.z, ph2))));
    ph3 = fmaf(x.x, va.w, fmaf(x.y, vb.w, fmaf(x.z, vc.w, fmaf(x.w, vd.w, ph3))));
  }
  *(bf8*)&ef16[(size_t)e * DD + part * 16] =
      (bf8){outv[0][0], outv[0][1], outv[0][2], outv[0][3],
            outv[1][0], outv[1][1], outv[1][2], outv[1][3]};
  *(bf8*)&ef16[(size_t)e * DD + part * 16 + 8] =
      (bf8){outv[2][0], outv[2][1], outv[2][2], outv[2][3],
            outv[3][0], outv[3][1], outv[3][2], outv[3][3]};
#pragma unroll
  for (int off = 1; off <= 2; off <<= 1) {
    ph0 += __shfl_xor(ph0, off, 64);
    ph1 += __shfl_xor(ph1, off, 64);
    ph2 += __shfl_xor(ph2, off, 64);
    ph3 += __shfl_xor(ph3, off, 64);
  }
  float pe = (part == 0) ? ph0 : (part == 1) ? ph1 : (part == 2) ? ph2 : ph3;
  araw[(size_t)e * NH + part] = pe + asrc0[src[e] * NH + part];
}

// gather v6: online softmax 4-wide; araw already includes asrc[src]
__global__ __launch_bounds__(256) void k_gather6(
    const __bf16* __restrict__ xh16, const float* __restrict__ araw,
    const int2* __restrict__ csr_pack, const int* __restrict__ offs,
    const float* __restrict__ asrc, const float* __restrict__ adst,
    const float* __restrict__ cb, const float* __restrict__ g,
    const float* __restrict__ bln, __bf16* __restrict__ nf16,
    float* __restrict__ nfout,
    const float* __restrict__ Wn, const float* __restrict__ asn,
    const float* __restrict__ adn, __bf16* __restrict__ xh16n,
    float* __restrict__ asrcn, float* __restrict__ adstn, int last) {
  int t = blockIdx.x * 4 + (threadIdx.x >> 6);
  int d = threadIdx.x & 63;
  if (t >= NN) return;
  int h = d >> 4;
  int o0 = offs[t], o1 = offs[t + 1];
  int deg = o1 - o0;
  float adh = adst[t * NH + h];

  float sh = asrc[t * NH + h] + adh;
  sh = ((sh > 0.f) ? sh : SLOPE * sh) * LOG2E;
  float m_run = sh;
  float wsum = 1.f;
  float acc = (float)xh16[(size_t)t * DD + d];

  int j = 0;
  for (; j + 3 < deg; j += 4) {
    int2 p0 = csr_pack[o0 + j], p1 = csr_pack[o0 + j + 1];
    int2 p2 = csr_pack[o0 + j + 2], p3 = csr_pack[o0 + j + 3];
    float ar0 = adh + araw[(size_t)p0.y * NH + h];
    float ar1 = adh + araw[(size_t)p1.y * NH + h];
    float ar2 = adh + araw[(size_t)p2.y * NH + h];
    float ar3 = adh + araw[(size_t)p3.y * NH + h];
    ar0 = ((ar0 > 0.f) ? ar0 : SLOPE * ar0) * LOG2E;
    ar1 = ((ar1 > 0.f) ? ar1 : SLOPE * ar1) * LOG2E;
    ar2 = ((ar2 > 0.f) ? ar2 : SLOPE * ar2) * LOG2E;
    ar3 = ((ar3 > 0.f) ? ar3 : SLOPE * ar3) * LOG2E;
    float x0 = (float)xh16[(size_t)p0.x * DD + d];
    float x1 = (float)xh16[(size_t)p1.x * DD + d];
    float x2 = (float)xh16[(size_t)p2.x * DD + d];
    float x3 = (float)xh16[(size_t)p3.x * DD + d];
    float mnew = fmaxf(fmaxf(m_run, fmaxf(ar0, ar1)), fmaxf(ar2, ar3));
    float rold = exp2f(m_run - mnew);
    float w0 = exp2f(ar0 - mnew), w1 = exp2f(ar1 - mnew);
    float w2 = exp2f(ar2 - mnew), w3 = exp2f(ar3 - mnew);
    acc = fmaf(w3, x3, fmaf(w2, x2, fmaf(w1, x1, fmaf(w0, x0, acc * rold))));
    wsum = (w0 + w1) + (w2 + w3) + wsum * rold;
    m_run = mnew;
  }
  for (; j < deg; ++j) {
    int2 p = csr_pack[o0 + j];
    float ar = adh + araw[(size_t)p.y * NH + h];
    ar = ((ar > 0.f) ? ar : SLOPE * ar) * LOG2E;
    float xv = (float)xh16[(size_t)p.x * DD + d];
    float mnew = fmaxf(m_run, ar);
    float rold = exp2f(m_run - mnew);
    float w = exp2f(ar - mnew);
    acc = fmaf(w, xv, acc * rold);
    wsum = fmaf(w, 1.f, wsum * rold);
    m_run = mnew;
  }

  float val = acc / (wsum + 1e-16f) + cb[d];
  float m = val;
#pragma unroll
  for (int off = 32; off >= 1; off >>= 1) m += __shfl_xor(m, off, 64);
  m *= (1.f / 64.f);
  float c = val - m;
  float q = c * c;
#pragma unroll
  for (int off = 32; off >= 1; off >>= 1) q += __shfl_xor(q, off, 64);
  float rstd = 1.f / sqrtf(q * (1.f / 64.f) + 1e-5f);
  float y = c * rstd * g[d] + bln[d];
  y = fmaxf(y, 0.f);
  float out = y + (float)nf16[(size_t)t * DD + d];
  nf16[(size_t)t * DD + d] = (__bf16)out;

  if (last) {
    nfout[(size_t)t * DD + d] = out;
  } else {
    float acc2 = 0.f;
#pragma unroll 8
    for (int k = 0; k < DD; ++k) {
      float xk = __shfl(out, k, 64);
      acc2 = fmaf(xk, Wn[k * DD + d], acc2);
    }
    xh16n[(size_t)t * DD + d] = (__bf16)acc2;
    int cc = d & 15;
    float ps = acc2 * asn[h * NC + cc];
    float pd = acc2 * adn[h * NC + cc];
#pragma unroll
    for (int off = 8; off >= 1; off >>= 1) {
      ps += __shfl_xor(ps, off, 64);
      pd += __shfl_xor(pd, off, 64);
    }
    if (cc == 0) { asrcn[t * NH + h] = ps; adstn[t * NH + h] = pd; }
  }
}

// ---------------- edge MLP v17: mlp16 + asrc_{l+1}[src] folded into araw ------
__global__ __launch_bounds__(256, 4) void k_edge_mlp17(
    const __bf16* __restrict__ nf16, __bf16* __restrict__ ef16,
    float* __restrict__ efout,
    const int* __restrict__ src, const int* __restrict__ dst,
    const __bf16* __restrict__ W1H, const float* __restrict__ b1,
    const float* __restrict__ g, const float* __restrict__ bg,
    const __bf16* __restrict__ W2H, const float* __restrict__ b2,
    const __bf16* __restrict__ W2VP, const __bf16* __restrict__ VP,
    const float* __restrict__ bvdot, const float* __restrict__ asrcn,
    float* __restrict__ araw, int last) {
  __shared__ __bf16 XH[EB * XSTR];
  __shared__ __bf16 RESB[EB * RSTR];
  __shared__ __bf16 Pb[EB * 8];
  int tid = threadIdx.x;
  int e0 = blockIdx.x * EB;
  float* XF = (float*)XH;

  {
    int row = tid >> 2, p = tid & 3;
    int se = src[e0 + row], de = dst[e0 + row];
    const bf8* psrc = (const bf8*)(nf16 + (size_t)se * DD + p * 16);
    *(bf8*)&XH[row * XSTR + p * 16]     = psrc[0];
    *(bf8*)&XH[row * XSTR + p * 16 + 8] = psrc[1];
    const bf8* pdst = (const bf8*)(nf16 + (size_t)de * DD + p * 16);
    *(bf8*)&XH[row * XSTR + 64 + p * 16]     = pdst[0];
    *(bf8*)&XH[row * XSTR + 64 + p * 16 + 8] = pdst[1];
    const bf8* pef = (const bf8*)(ef16 + (size_t)(e0 + row) * DD + p * 16);
    bf8 ev0 = pef[0], ev1 = pef[1];
    *(bf8*)&XH[row * XSTR + 128 + p * 16]     = ev0;
    *(bf8*)&XH[row * XSTR + 128 + p * 16 + 8] = ev1;
    *(bf8*)&RESB[row * RSTR + p * 16]     = ev0;
    *(bf8*)&RESB[row * RSTR + p * 16 + 8] = ev1;
  }
  __syncthreads();

  int cg = tid >> 6, l = tid & 63;
  int gq = l >> 4, i = l & 15;
  int col = cg * 16 + i;

  f32x4 acc[4][3];
#pragma unroll
  for (int rt = 0; rt < 4; ++rt)
#pragma unroll
    for (int t = 0; t < 3; ++t) acc[rt][t] = (f32x4){0.f, 0.f, 0.f, 0.f};
  f32x4 accQ = (f32x4){0.f, 0.f, 0.f, 0.f};

#pragma unroll
  for (int s = 0; s < 6; ++s) {
    bf8 a[4];
#pragma unroll
    for (int rt = 0; rt < 4; ++rt)
      a[rt] = *(const bf8*)&XH[(rt * 16 + i) * XSTR + s * 32 + gq * 8];
#pragma unroll
    for (int t = 0; t < 3; ++t) {
      bf8 bh = *(const bf8*)(W1H + ((size_t)((cg * 3 + t) * 6 + s) * 64 + l) * 8);
#pragma unroll
      for (int rt = 0; rt < 4; ++rt) acc[rt][t] = MFMA(a[rt], bh, acc[rt][t]);
    }
  }

  float b1v[3], gv[3], bgv[3];
#pragma unroll
  for (int t = 0; t < 3; ++t) {
    int n = cg * 48 + t * 16 + i;
    b1v[t] = b1[n]; gv[t] = g[n]; bgv[t] = bg[n];
  }
#pragma unroll
  for (int rt = 0; rt < 4; ++rt)
#pragma unroll
    for (int t = 0; t < 3; ++t)
#pragma unroll
      for (int r = 0; r < 4; ++r) acc[rt][t][r] += b1v[t];

#pragma unroll
  for (int rt = 0; rt < 4; ++rt)
#pragma unroll
    for (int r = 0; r < 4; ++r) {
      float sm = 0.f, sq = 0.f;
#pragma unroll
      for (int t = 0; t < 3; ++t) { float x = acc[rt][t][r]; sm += x; sq = fmaf(x, x, sq); }
#pragma unroll
      for (int off = 1; off <= 8; off <<= 1) {
        sm += __shfl_xor(sm, off, 64);
        sq += __shfl_xor(sq, off, 64);
      }
      if (i == 0) {
        int row = rt * 16 + gq * 4 + r;
        bf2 pr; pr[0] = (__bf16)sm; pr[1] = (__bf16)sq;
        *(bf2*)&Pb[row * 8 + cg * 2] = pr;
      }
    }
  __syncthreads();   // barrier 1

  if (tid < EB) {
    bf8 pv = *(const bf8*)&Pb[tid * 8];
    float sm = (float)pv[0] + (float)pv[2] + (float)pv[4] + (float)pv[6];
    float sq = (float)pv[1] + (float)pv[3] + (float)pv[5] + (float)pv[7];
    float mean = sm * (1.f / (float)DIN);
    float var = sq * (1.f / (float)DIN) - mean * mean;
    float rstd = 1.f / sqrtf(var + 1e-5f);
    bf2 mv; mv[0] = (__bf16)mean; mv[1] = (__bf16)rstd;
    *(bf2*)&Pb[tid * 8] = mv;
  }
  __syncthreads();   // barrier 2

#pragma unroll
  for (int rt = 0; rt < 4; ++rt)
#pragma unroll
    for (int r = 0; r < 4; ++r) {
      int row = rt * 16 + gq * 4 + r;
      bf2 mv = *(const bf2*)&Pb[row * 8];
      float mean = (float)mv[0], rstd = (float)mv[1];
#pragma unroll
      for (int t = 0; t < 3; ++t) {
        float y = (acc[rt][t][r] - mean) * rstd * gv[t] + bgv[t];
        y = fmaxf(y, 0.f);
        XH[row * XSTR + cg * 48 + t * 16 + i] = (__bf16)y;
      }
    }
  __syncthreads();   // barrier 3

  f32x4 acc2[4];
#pragma unroll
  for (int rt = 0; rt < 4; ++rt) acc2[rt] = (f32x4){0.f, 0.f, 0.f, 0.f};

#pragma unroll
  for (int s = 0; s < 6; ++s) {
    bf8 a2[4];
#pragma unroll
    for (int rt = 0; rt < 4; ++rt)
      a2[rt] = *(const bf8*)&XH[(rt * 16 + i) * XSTR + s * 32 + gq * 8];
    bf8 bh = *(const bf8*)(W2H + ((size_t)(cg * 6 + s) * 64 + l) * 8);
#pragma unroll
    for (int rt = 0; rt < 4; ++rt) acc2[rt] = MFMA(a2[rt], bh, acc2[rt]);
    if (!last) {
      bf8 acg = *(const bf8*)&XH[(cg * 16 + i) * XSTR + s * 32 + gq * 8];
      bf8 wv = *(const bf8*)(W2VP + ((size_t)(s * 64 + l)) * 8);
      accQ = MFMA(acg, wv, accQ);
    }
  }
  if (!last) {
#pragma unroll
    for (int s2 = 0; s2 < 2; ++s2) {
      bf8 ae = *(const bf8*)&RESB[(cg * 16 + i) * RSTR + s2 * 32 + gq * 8];
      bf8 vp = *(const bf8*)(VP + ((size_t)(s2 * 64 + l)) * 8);
      accQ = MFMA(ae, vp, accQ);
    }
  }
  __syncthreads();   // barrier 4

  float b2v = b2[col];
#pragma unroll
  for (int rt = 0; rt < 4; ++rt)
#pragma unroll
    for (int r = 0; r < 4; ++r) {
      int row = rt * 16 + gq * 4 + r;
      float resv = (float)RESB[row * RSTR + col];
      XF[row * FSTR + col] = acc2[rt][r] + b2v + resv;
    }

  if (!last && i < 4) {
    float bvd = bvdot[i];
#pragma unroll
    for (int r = 0; r < 4; ++r) {
      int row = cg * 16 + gq * 4 + r;
      int se2 = src[e0 + row];
      araw[(size_t)(e0 + row) * NH + i] = accQ[r] + bvd + asrcn[se2 * NH + i];
    }
  }
  __syncthreads();   // barrier 5

  {
    int row = tid >> 2, q = tid & 3;
    const float* fr = &XF[row * FSTR + q * 16];
    if (last) {
      float* op = efout + (size_t)(e0 + row) * DD + q * 16;
#pragma unroll
      for (int k = 0; k < 4; ++k)
        *(float4*)(op + k * 4) = *(const float4*)(fr + k * 4);
    } else {
      bf8 o0, o1;
#pragma unroll
      for (int k = 0; k < 8; ++k) { o0[k] = (__bf16)fr[k]; o1[k] = (__bf16)fr[k + 8]; }
      __bf16* op = ef16 + (size_t)(e0 + row) * DD + q * 16;
      *(bf8*)op = o0;
      *(bf8*)(op + 8) = o1;
    }
  }
}

extern "C" void kernel_launch(void* const* d_in, const int* in_sizes, int n_in,
                              void* d_out, int out_size, void* d_ws, size_t ws_size,
                              hipStream_t stream) {
  const float* node_feats = (const float*)d_in[0];
  const float* edge_feats = (const float*)d_in[1];
  const int*   edge_index = (const int*)d_in[2];
  const float* conv_w  = (const float*)d_in[3];
  const float* att_src = (const float*)d_in[4];
  const float* att_dst = (const float*)d_in[5];
  const float* edge_w  = (const float*)d_in[6];
  const float* att_edge= (const float*)d_in[7];
  const float* conv_b  = (const float*)d_in[8];
  const float* ln_g    = (const float*)d_in[9];
  const float* ln_b    = (const float*)d_in[10];
  const float* up1_w   = (const float*)d_in[11];
  const float* up1_b   = (const float*)d_in[12];
  const float* up_ln_g = (const float*)d_in[13];
  const float* up_ln_b = (const float*)d_in[14];
  const float* up2_w   = (const float*)d_in[15];
  const float* up2_b   = (const float*)d_in[16];

  const int* src = edge_index;
  const int* dst = edge_index + NE;

  float* nf = (float*)d_out;
  float* efout = nf + (size_t)NN * DD;

  float* w = (float*)d_ws;
  __bf16* xh16a = (__bf16*)w; w += (size_t)NN * DD / 2;
  __bf16* xh16b = (__bf16*)w; w += (size_t)NN * DD / 2;
  __bf16* nf16 = (__bf16*)w; w += (size_t)NN * DD / 2;
  __bf16* ef16 = (__bf16*)w; w += (size_t)NE * DD / 2;
  float* asA   = w; w += (size_t)NN * NH;
  float* adA   = w; w += (size_t)NN * NH;
  float* asB   = w; w += (size_t)NN * NH;
  float* adB   = w; w += (size_t)NN * NH;
  float* araw  = w; w += (size_t)NE * NH;
  float* vbuf  = w; w += 4 * 256;
  float* bvdot = w; w += 16;
  __bf16* W1H  = (__bf16*)w; w += (size_t)4 * 36864 / 2;
  __bf16* W2H  = (__bf16*)w; w += (size_t)4 * 12288 / 2;
  __bf16* W2VP = (__bf16*)w; w += (size_t)3 * 3072 / 2;
  __bf16* VPb  = (__bf16*)w; w += (size_t)3 * 1024 / 2;
  int* deg     = (int*)w; w += NN;
  int* offs    = (int*)w; w += NN + 2;
  int* cursor  = (int*)w; w += NN;
  int* bsum    = (int*)w; w += 128;
  int* boff    = (int*)w; w += 128;
  int2* csr_pack = (int2*)w; w += (size_t)NE * 2;

  __bf16* xh[2] = {xh16a, xh16b};
  float* as_[2] = {asA, asB};
  float* ad_[2] = {adA, adB};

  k_pack_w1<<<72, 256, 0, stream>>>(up1_w, W1H);
  k_pack_w2<<<24, 256, 0, stream>>>(up2_w, W2H);

  const int nb = (NN + 1023) / 1024;
  k_zero<<<(NN + 255) / 256, 256, 0, stream>>>(deg);
  k_hist<<<(NE + 255) / 256, 256, 0, stream>>>(dst, deg);
  k_scan1<<<nb, 256, 0, stream>>>(deg, offs, bsum);
  k_scan2<<<1, 64, 0, stream>>>(bsum, boff, offs, nb);
  k_scan3<<<(NN + 255) / 256, 256, 0, stream>>>(offs, boff, cursor);
  k_scatter<<<(NE + 255) / 256, 256, 0, stream>>>(src, dst, cursor, csr_pack);

  k_v_all<<<4, 256, 0, stream>>>(edge_w, att_edge, vbuf);
  k_w2v<<<3, 384, 0, stream>>>(up2_w, up2_b, vbuf, W2VP, VPb, bvdot);
  k_xh0<<<NN / 4 + 1, 256, 0, stream>>>(node_feats, conv_w, att_src, att_dst,
                                        nf16, xh16a, asA, adA);
  // layer-0 araw includes asrc0[src] (asA written by k_xh0 above)
  k_pass1f<<<NE / 64, 256, 0, stream>>>(edge_feats, vbuf, src, asA, ef16, araw);

  for (int l = 0; l < NL; ++l) {
    int last = (l == NL - 1) ? 1 : 0;
    int cur = l & 1, nxt = (l + 1) & 1;
    k_gather6<<<NN / 4 + 1, 256, 0, stream>>>(
        xh[cur], araw, csr_pack, offs, as_[cur], ad_[cur],
        conv_b + (size_t)l * DD, ln_g + (size_t)l * DD, ln_b + (size_t)l * DD,
        nf16, nf,
        last ? conv_w : (conv_w + (size_t)(l + 1) * DD * DD),
        last ? att_src : (att_src + (size_t)(l + 1) * NH * NC),
        last ? att_dst : (att_dst + (size_t)(l + 1) * NH * NC),
        xh[nxt], as_[nxt], ad_[nxt], last);
    k_edge_mlp17<<<NE / EB, 256, 0, stream>>>(
        nf16, ef16, efout, src, dst,
        W1H + (size_t)l * 36864, up1_b + (size_t)l * DIN,
        up_ln_g + (size_t)l * DIN, up_ln_b + (size_t)l * DIN,
        W2H + (size_t)l * 12288, up2_b + (size_t)l * DD,
        last ? W2VP : (W2VP + (size_t)l * 3072),
        last ? VPb : (VPb + (size_t)l * 1024),
        bvdot + (size_t)l * 4, as_[nxt], araw, last);
  }
}

// Round 24
// 2523.658 us; speedup vs baseline: 1.0096x; 1.0096x over previous
//
#include <hip/hip_runtime.h>
#include <math.h>

#define NN 100000
#define NE 1600000
#define DD 64
#define NL 4
#define NH 4
#define NC 16
#define DIN 192
#define SLOPE 0.2f
#define EB 64
#define XSTR 200
#define FSTR 66
#define RSTR 68
#define LOG2E 1.44269504088896340736f

typedef __bf16 bf8 __attribute__((ext_vector_type(8)));
typedef __bf16 bf4 __attribute__((ext_vector_type(4)));
typedef __bf16 bf2 __attribute__((ext_vector_type(2)));
typedef float f32x4 __attribute__((ext_vector_type(4)));

__device__ __forceinline__ f32x4 MFMA(bf8 a, bf8 b, f32x4 c) {
  return __builtin_amdgcn_mfma_f32_16x16x32_bf16(a, b, c, 0, 0, 0);
}

// ---------------- merged prep: pack_w1 | pack_w2 | v_all | zero-deg ----------
__global__ void k_prep(const float* __restrict__ up1_w, const float* __restrict__ up2_w,
                       const float* __restrict__ ew_all, const float* __restrict__ ae_all,
                       __bf16* __restrict__ W1H, __bf16* __restrict__ W2H,
                       float* __restrict__ vbuf, int* __restrict__ deg) {
  int bid = blockIdx.x;
  int tid = threadIdx.x;
  if (bid < 72) {                       // pack W1 (4 layers)
    int gidx = bid * 256 + tid;
    if (gidx >= 4 * 4608) return;
    int lyr = gidx / 4608, rem = gidx % 4608;
    int lane = rem & 63, ts = rem >> 6;
    int s = ts % 6, t = ts / 6;
    const float* Wl = up1_w + (size_t)lyr * DIN * DIN;
    size_t base = (size_t)lyr * 36864 + ((size_t)(t * 6 + s) * 64 + lane) * 8;
    int k0 = s * 32 + (lane >> 4) * 8, n = t * 16 + (lane & 15);
#pragma unroll
    for (int j = 0; j < 8; ++j)
      W1H[base + j] = (__bf16)Wl[(size_t)(k0 + j) * DIN + n];
  } else if (bid < 96) {                // pack W2 (4 layers)
    int gidx = (bid - 72) * 256 + tid;
    if (gidx >= 4 * 1536) return;
    int lyr = gidx / 1536, rem = gidx % 1536;
    int lane = rem & 63, ts = rem >> 6;
    int s = ts % 6, t = ts / 6;
    const float* Wl = up2_w + (size_t)lyr * DIN * DD;
    size_t base = (size_t)lyr * 12288 + ((size_t)(t * 6 + s) * 64 + lane) * 8;
    int k0 = s * 32 + (lane >> 4) * 8, n = t * 16 + (lane & 15);
#pragma unroll
    for (int j = 0; j < 8; ++j)
      W2H[base + j] = (__bf16)Wl[(size_t)(k0 + j) * DD + n];
  } else if (bid < 100) {               // v_all (4 layers)
    int l = bid - 96;
    const float* ew = ew_all + (size_t)l * DD * DD;
    const float* ae = ae_all + (size_t)l * NH * NC;
    int d = tid >> 2, h = tid & 3;
    float s = 0.f;
#pragma unroll
    for (int c = 0; c < NC; ++c) s = fmaf(ew[d * DD + h * NC + c], ae[h * NC + c], s);
    vbuf[l * 256 + d * NH + h] = s;
  } else {                              // zero deg
    int i = (bid - 100) * 256 + tid;
    if (i < NN) deg[i] = 0;
  }
}

// W2VP[l] = W2_l @ v_{l+1}; VP[l] = v_{l+1}; bvdot[l][h] = b2_l . v_{l+1}[:,h]
__global__ void k_w2v(const float* __restrict__ up2_w, const float* __restrict__ up2_b,
                      const float* __restrict__ vbuf, __bf16* __restrict__ W2VP,
                      __bf16* __restrict__ VP, float* __restrict__ bvdot) {
  int l = blockIdx.x;
  const float* vn = vbuf + (l + 1) * 256;
  int t = threadIdx.x;
  if (t < 384) {
    int s = t >> 6, lane = t & 63;
    int i = lane & 15, k0 = s * 32 + (lane >> 4) * 8;
    const float* W2 = up2_w + (size_t)l * DIN * DD;
    __bf16* out = W2VP + (size_t)l * 3072 + ((size_t)(s * 64 + lane)) * 8;
#pragma unroll
    for (int j = 0; j < 8; ++j) {
      float val = 0.f;
      if (i < 4)
        for (int n = 0; n < DD; ++n)
          val = fmaf(W2[(size_t)(k0 + j) * DD + n], vn[n * NH + i], val);
      out[j] = (__bf16)val;
    }
  }
  if (t < 128) {
    int s2 = t >> 6, lane = t & 63;
    int i = lane & 15, k0 = s2 * 32 + (lane >> 4) * 8;
    __bf16* out = VP + (size_t)l * 1024 + ((size_t)(s2 * 64 + lane)) * 8;
#pragma unroll
    for (int j = 0; j < 8; ++j)
      out[j] = (i < 4) ? (__bf16)vn[(k0 + j) * NH + i] : (__bf16)0.f;
  }
  if (t < 4) {
    const float* b2 = up2_b + (size_t)l * DD;
    float bv = 0.f;
    for (int n = 0; n < DD; ++n) bv = fmaf(b2[n], vn[n * NH + t], bv);
    bvdot[l * 4 + t] = bv;
  }
}

// ---------------- CSR build ----------------
__global__ void k_hist(const int* __restrict__ dst, int* __restrict__ deg) {
  int e = blockIdx.x * 256 + threadIdx.x;
  if (e < NE) atomicAdd(&deg[dst[e]], 1);
}

__global__ void k_scan1(const int* __restrict__ deg, int* __restrict__ offs,
                        int* __restrict__ bsum) {
  __shared__ int sh[256];
  int t = threadIdx.x, b = blockIdx.x;
  int i0 = b * 1024 + t * 4;
  int d0 = (i0 + 0 < NN) ? deg[i0 + 0] : 0;
  int d1 = (i0 + 1 < NN) ? deg[i0 + 1] : 0;
  int d2 = (i0 + 2 < NN) ? deg[i0 + 2] : 0;
  int d3 = (i0 + 3 < NN) ? deg[i0 + 3] : 0;
  int s4 = d0 + d1 + d2 + d3;
  sh[t] = s4;
  __syncthreads();
  int p = 0;
#pragma unroll
  for (int off = 1; off < 256; off <<= 1) {
    int v = (t >= off) ? sh[t - off] : 0;
    __syncthreads();
    sh[t] += v;
    __syncthreads();
  }
  p = sh[t] - s4;
  if (t == 255) bsum[b] = sh[255];
  if (i0 + 0 < NN) offs[i0 + 0] = p;
  if (i0 + 1 < NN) offs[i0 + 1] = p + d0;
  if (i0 + 2 < NN) offs[i0 + 2] = p + d0 + d1;
  if (i0 + 3 < NN) offs[i0 + 3] = p + d0 + d1 + d2;
}

__global__ void k_scan2(int* __restrict__ bsum, int* __restrict__ boff,
                        int* __restrict__ offs, int nb) {
  if (threadIdx.x == 0 && blockIdx.x == 0) {
    int run = 0;
    for (int k = 0; k < nb; ++k) { boff[k] = run; run += bsum[k]; }
    offs[NN] = NE;
  }
}

__global__ void k_scan3(int* __restrict__ offs, const int* __restrict__ boff,
                        int* __restrict__ cursor) {
  int i = blockIdx.x * 256 + threadIdx.x;
  if (i < NN) {
    int v = offs[i] + boff[i >> 10];
    offs[i] = v;
    cursor[i] = v;
  }
}

// packed CSR: csr_pack[pos] = (src[e], e)
__global__ void k_scatter(const int* __restrict__ src, const int* __restrict__ dst,
                          int* __restrict__ cursor, int2* __restrict__ csr_pack) {
  int e = blockIdx.x * 256 + threadIdx.x;
  if (e >= NE) return;
  int pos = atomicAdd(&cursor[dst[e]], 1);
  csr_pack[pos] = make_int2(src[e], e);
}

// ---------------- merged: layer-0 xh (node side) | pass1f (edge side) --------
__global__ void k_xh0p1(const float* __restrict__ node_feats,
                        const float* __restrict__ edge_feats,
                        const float* __restrict__ W, const float* __restrict__ as_,
                        const float* __restrict__ ad_, const float* __restrict__ v,
                        __bf16* __restrict__ nf16, __bf16* __restrict__ xh16,
                        float* __restrict__ asrc, float* __restrict__ adst,
                        __bf16* __restrict__ ef16, float* __restrict__ araw) {
  int bid = blockIdx.x;
  if (bid < NN / 4 + 1) {
    // xh0 role
    int t = bid * 4 + (threadIdx.x >> 6);
    int d = threadIdx.x & 63;
    if (t >= NN) return;
    const float* x = node_feats + (size_t)t * DD;
    nf16[(size_t)t * DD + d] = (__bf16)x[d];
    float acc = 0.f;
#pragma unroll
    for (int k = 0; k < DD; ++k) acc = fmaf(x[k], W[k * DD + d], acc);
    xh16[(size_t)t * DD + d] = (__bf16)acc;
    int h = d >> 4, c = d & 15;
    float ps = acc * as_[h * NC + c];
    float pd = acc * ad_[h * NC + c];
#pragma unroll
    for (int off = 8; off >= 1; off >>= 1) {
      ps += __shfl_xor(ps, off, 64);
      pd += __shfl_xor(pd, off, 64);
    }
    if (c == 0) { asrc[t * NH + h] = ps; adst[t * NH + h] = pd; }
  } else {
    // pass1f role: edge_feats -> ef16 + RAW pe into araw[e]
    int e = (bid - (NN / 4 + 1)) * 64 + (threadIdx.x >> 2);
    int part = threadIdx.x & 3;
    if (e >= NE) return;
    float ph0 = 0.f, ph1 = 0.f, ph2 = 0.f, ph3 = 0.f;
    const float4* ep = (const float4*)(edge_feats + (size_t)e * DD + part * 16);
    const float4* v4 = (const float4*)v;
    bf4 outv[4];
#pragma unroll
    for (int c4 = 0; c4 < 4; ++c4) {
      float4 x = ep[c4];
      outv[c4][0] = (__bf16)x.x; outv[c4][1] = (__bf16)x.y;
      outv[c4][2] = (__bf16)x.z; outv[c4][3] = (__bf16)x.w;
      int d0 = part * 16 + c4 * 4;
      float4 va = v4[d0], vb = v4[d0 + 1], vc = v4[d0 + 2], vd = v4[d0 + 3];
      ph0 = fmaf(x.x, va.x, fmaf(x.y, vb.x, fmaf(x.z, vc.x, fmaf(x.w, vd.x, ph0))));
      ph1 = fmaf(x.x, va.y, fmaf(x.y, vb.y, fmaf(x.z, vc.y, fmaf(x.w, vd.y, ph1))));
      ph2 = fmaf(x.x, va.z, fmaf(x.y, vb.z, fmaf(x.z, vc.z, fmaf(x.w, vd.z, ph2))));
      ph3 = fmaf(x.x, va.w, fmaf(x.y, vb.w, fmaf(x.z, vc.w, fmaf(x.w, vd.w, ph3))));
    }
    *(bf8*)&ef16[(size_t)e * DD + part * 16] =
        (bf8){outv[0][0], outv[0][1], outv[0][2], outv[0][3],
              outv[1][0], outv[1][1], outv[1][2], outv[1][3]};
    *(bf8*)&ef16[(size_t)e * DD + part * 16 + 8] =
        (bf8){outv[2][0], outv[2][1], outv[2][2], outv[2][3],
              outv[3][0], outv[3][1], outv[3][2], outv[3][3]};
#pragma unroll
    for (int off = 1; off <= 2; off <<= 1) {
      ph0 += __shfl_xor(ph0, off, 64);
      ph1 += __shfl_xor(ph1, off, 64);
      ph2 += __shfl_xor(ph2, off, 64);
      ph3 += __shfl_xor(ph3, off, 64);
    }
    float pe = (part == 0) ? ph0 : (part == 1) ? ph1 : (part == 2) ? ph2 : ph3;
    araw[(size_t)e * NH + part] = pe;
  }
}

// gather v5 (R22 best): online softmax 4-wide + packed CSR + fused next-layer xh
__global__ __launch_bounds__(256) void k_gather5(
    const __bf16* __restrict__ xh16, const float* __restrict__ araw,
    const int2* __restrict__ csr_pack, const int* __restrict__ offs,
    const float* __restrict__ asrc, const float* __restrict__ adst,
    const float* __restrict__ cb, const float* __restrict__ g,
    const float* __restrict__ bln, __bf16* __restrict__ nf16,
    float* __restrict__ nfout,
    const float* __restrict__ Wn, const float* __restrict__ asn,
    const float* __restrict__ adn, __bf16* __restrict__ xh16n,
    float* __restrict__ asrcn, float* __restrict__ adstn, int last) {
  int t = blockIdx.x * 4 + (threadIdx.x >> 6);
  int d = threadIdx.x & 63;
  if (t >= NN) return;
  int h = d >> 4;
  int o0 = offs[t], o1 = offs[t + 1];
  int deg = o1 - o0;
  float adh = adst[t * NH + h];

  float sh = asrc[t * NH + h] + adh;
  sh = ((sh > 0.f) ? sh : SLOPE * sh) * LOG2E;
  float m_run = sh;
  float wsum = 1.f;
  float acc = (float)xh16[(size_t)t * DD + d];

  int j = 0;
  for (; j + 3 < deg; j += 4) {
    int2 p0 = csr_pack[o0 + j], p1 = csr_pack[o0 + j + 1];
    int2 p2 = csr_pack[o0 + j + 2], p3 = csr_pack[o0 + j + 3];
    float ar0 = asrc[p0.x * NH + h] + adh + araw[(size_t)p0.y * NH + h];
    float ar1 = asrc[p1.x * NH + h] + adh + araw[(size_t)p1.y * NH + h];
    float ar2 = asrc[p2.x * NH + h] + adh + araw[(size_t)p2.y * NH + h];
    float ar3 = asrc[p3.x * NH + h] + adh + araw[(size_t)p3.y * NH + h];
    ar0 = ((ar0 > 0.f) ? ar0 : SLOPE * ar0) * LOG2E;
    ar1 = ((ar1 > 0.f) ? ar1 : SLOPE * ar1) * LOG2E;
    ar2 = ((ar2 > 0.f) ? ar2 : SLOPE * ar2) * LOG2E;
    ar3 = ((ar3 > 0.f) ? ar3 : SLOPE * ar3) * LOG2E;
    float x0 = (float)xh16[(size_t)p0.x * DD + d];
    float x1 = (float)xh16[(size_t)p1.x * DD + d];
    float x2 = (float)xh16[(size_t)p2.x * DD + d];
    float x3 = (float)xh16[(size_t)p3.x * DD + d];
    float mnew = fmaxf(fmaxf(m_run, fmaxf(ar0, ar1)), fmaxf(ar2, ar3));
    float rold = exp2f(m_run - mnew);
    float w0 = exp2f(ar0 - mnew), w1 = exp2f(ar1 - mnew);
    float w2 = exp2f(ar2 - mnew), w3 = exp2f(ar3 - mnew);
    acc = fmaf(w3, x3, fmaf(w2, x2, fmaf(w1, x1, fmaf(w0, x0, acc * rold))));
    wsum = (w0 + w1) + (w2 + w3) + wsum * rold;
    m_run = mnew;
  }
  for (; j < deg; ++j) {
    int2 p = csr_pack[o0 + j];
    float ar = asrc[p.x * NH + h] + adh + araw[(size_t)p.y * NH + h];
    ar = ((ar > 0.f) ? ar : SLOPE * ar) * LOG2E;
    float xv = (float)xh16[(size_t)p.x * DD + d];
    float mnew = fmaxf(m_run, ar);
    float rold = exp2f(m_run - mnew);
    float w = exp2f(ar - mnew);
    acc = fmaf(w, xv, acc * rold);
    wsum = fmaf(w, 1.f, wsum * rold);
    m_run = mnew;
  }

  float val = acc / (wsum + 1e-16f) + cb[d];
  float m = val;
#pragma unroll
  for (int off = 32; off >= 1; off >>= 1) m += __shfl_xor(m, off, 64);
  m *= (1.f / 64.f);
  float c = val - m;
  float q = c * c;
#pragma unroll
  for (int off = 32; off >= 1; off >>= 1) q += __shfl_xor(q, off, 64);
  float rstd = 1.f / sqrtf(q * (1.f / 64.f) + 1e-5f);
  float y = c * rstd * g[d] + bln[d];
  y = fmaxf(y, 0.f);
  float out = y + (float)nf16[(size_t)t * DD + d];
  nf16[(size_t)t * DD + d] = (__bf16)out;

  if (last) {
    nfout[(size_t)t * DD + d] = out;
  } else {
    float acc2 = 0.f;
#pragma unroll 8
    for (int k = 0; k < DD; ++k) {
      float xk = __shfl(out, k, 64);
      acc2 = fmaf(xk, Wn[k * DD + d], acc2);
    }
    xh16n[(size_t)t * DD + d] = (__bf16)acc2;
    int cc = d & 15;
    float ps = acc2 * asn[h * NC + cc];
    float pd = acc2 * adn[h * NC + cc];
#pragma unroll
    for (int off = 8; off >= 1; off >>= 1) {
      ps += __shfl_xor(ps, off, 64);
      pd += __shfl_xor(pd, off, 64);
    }
    if (cc == 0) { asrcn[t * NH + h] = ps; adstn[t * NH + h] = pd; }
  }
}

// ---------------- edge MLP v16 (R22 best): pe via accQ over [H | ef_old] ------
__global__ __launch_bounds__(256, 4) void k_edge_mlp16(
    const __bf16* __restrict__ nf16, __bf16* __restrict__ ef16,
    float* __restrict__ efout,
    const int* __restrict__ src, const int* __restrict__ dst,
    const __bf16* __restrict__ W1H, const float* __restrict__ b1,
    const float* __restrict__ g, const float* __restrict__ bg,
    const __bf16* __restrict__ W2H, const float* __restrict__ b2,
    const __bf16* __restrict__ W2VP, const __bf16* __restrict__ VP,
    const float* __restrict__ bvdot, float* __restrict__ araw, int last) {
  __shared__ __bf16 XH[EB * XSTR];
  __shared__ __bf16 RESB[EB * RSTR];
  __shared__ __bf16 Pb[EB * 8];
  int tid = threadIdx.x;
  int e0 = blockIdx.x * EB;
  float* XF = (float*)XH;

  {
    int row = tid >> 2, p = tid & 3;
    int se = src[e0 + row], de = dst[e0 + row];
    const bf8* psrc = (const bf8*)(nf16 + (size_t)se * DD + p * 16);
    *(bf8*)&XH[row * XSTR + p * 16]     = psrc[0];
    *(bf8*)&XH[row * XSTR + p * 16 + 8] = psrc[1];
    const bf8* pdst = (const bf8*)(nf16 + (size_t)de * DD + p * 16);
    *(bf8*)&XH[row * XSTR + 64 + p * 16]     = pdst[0];
    *(bf8*)&XH[row * XSTR + 64 + p * 16 + 8] = pdst[1];
    const bf8* pef = (const bf8*)(ef16 + (size_t)(e0 + row) * DD + p * 16);
    bf8 ev0 = pef[0], ev1 = pef[1];
    *(bf8*)&XH[row * XSTR + 128 + p * 16]     = ev0;
    *(bf8*)&XH[row * XSTR + 128 + p * 16 + 8] = ev1;
    *(bf8*)&RESB[row * RSTR + p * 16]     = ev0;
    *(bf8*)&RESB[row * RSTR + p * 16 + 8] = ev1;
  }
  __syncthreads();

  int cg = tid >> 6, l = tid & 63;
  int gq = l >> 4, i = l & 15;
  int col = cg * 16 + i;

  f32x4 acc[4][3];
#pragma unroll
  for (int rt = 0; rt < 4; ++rt)
#pragma unroll
    for (int t = 0; t < 3; ++t) acc[rt][t] = (f32x4){0.f, 0.f, 0.f, 0.f};
  f32x4 accQ = (f32x4){0.f, 0.f, 0.f, 0.f};

#pragma unroll
  for (int s = 0; s < 6; ++s) {
    bf8 a[4];
#pragma unroll
    for (int rt = 0; rt < 4; ++rt)
      a[rt] = *(const bf8*)&XH[(rt * 16 + i) * XSTR + s * 32 + gq * 8];
#pragma unroll
    for (int t = 0; t < 3; ++t) {
      bf8 bh = *(const bf8*)(W1H + ((size_t)((cg * 3 + t) * 6 + s) * 64 + l) * 8);
#pragma unroll
      for (int rt = 0; rt < 4; ++rt) acc[rt][t] = MFMA(a[rt], bh, acc[rt][t]);
    }
  }

  float b1v[3], gv[3], bgv[3];
#pragma unroll
  for (int t = 0; t < 3; ++t) {
    int n = cg * 48 + t * 16 + i;
    b1v[t] = b1[n]; gv[t] = g[n]; bgv[t] = bg[n];
  }
#pragma unroll
  for (int rt = 0; rt < 4; ++rt)
#pragma unroll
    for (int t = 0; t < 3; ++t)
#pragma unroll
      for (int r = 0; r < 4; ++r) acc[rt][t][r] += b1v[t];

#pragma unroll
  for (int rt = 0; rt < 4; ++rt)
#pragma unroll
    for (int r = 0; r < 4; ++r) {
      float sm = 0.f, sq = 0.f;
#pragma unroll
      for (int t = 0; t < 3; ++t) { float x = acc[rt][t][r]; sm += x; sq = fmaf(x, x, sq); }
#pragma unroll
      for (int off = 1; off <= 8; off <<= 1) {
        sm += __shfl_xor(sm, off, 64);
        sq += __shfl_xor(sq, off, 64);
      }
      if (i == 0) {
        int row = rt * 16 + gq * 4 + r;
        bf2 pr; pr[0] = (__bf16)sm; pr[1] = (__bf16)sq;
        *(bf2*)&Pb[row * 8 + cg * 2] = pr;
      }
    }
  __syncthreads();   // barrier 1

  if (tid < EB) {
    bf8 pv = *(const bf8*)&Pb[tid * 8];
    float sm = (float)pv[0] + (float)pv[2] + (float)pv[4] + (float)pv[6];
    float sq = (float)pv[1] + (float)pv[3] + (float)pv[5] + (float)pv[7];
    float mean = sm * (1.f / (float)DIN);
    float var = sq * (1.f / (float)DIN) - mean * mean;
    float rstd = 1.f / sqrtf(var + 1e-5f);
    bf2 mv; mv[0] = (__bf16)mean; mv[1] = (__bf16)rstd;
    *(bf2*)&Pb[tid * 8] = mv;
  }
  __syncthreads();   // barrier 2

#pragma unroll
  for (int rt = 0; rt < 4; ++rt)
#pragma unroll
    for (int r = 0; r < 4; ++r) {
      int row = rt * 16 + gq * 4 + r;
      bf2 mv = *(const bf2*)&Pb[row * 8];
      float mean = (float)mv[0], rstd = (float)mv[1];
#pragma unroll
      for (int t = 0; t < 3; ++t) {
        float y = (acc[rt][t][r] - mean) * rstd * gv[t] + bgv[t];
        y = fmaxf(y, 0.f);
        XH[row * XSTR + cg * 48 + t * 16 + i] = (__bf16)y;
      }
    }
  __syncthreads();   // barrier 3

  f32x4 acc2[4];
#pragma unroll
  for (int rt = 0; rt < 4; ++rt) acc2[rt] = (f32x4){0.f, 0.f, 0.f, 0.f};

#pragma unroll
  for (int s = 0; s < 6; ++s) {
    bf8 a2[4];
#pragma unroll
    for (int rt = 0; rt < 4; ++rt)
      a2[rt] = *(const bf8*)&XH[(rt * 16 + i) * XSTR + s * 32 + gq * 8];
    bf8 bh = *(const bf8*)(W2H + ((size_t)(cg * 6 + s) * 64 + l) * 8);
#pragma unroll
    for (int rt = 0; rt < 4; ++rt) acc2[rt] = MFMA(a2[rt], bh, acc2[rt]);
    if (!last) {
      bf8 acg = *(const bf8*)&XH[(cg * 16 + i) * XSTR + s * 32 + gq * 8];
      bf8 wv = *(const bf8*)(W2VP + ((size_t)(s * 64 + l)) * 8);
      accQ = MFMA(acg, wv, accQ);
    }
  }
  if (!last) {
#pragma unroll
    for (int s2 = 0; s2 < 2; ++s2) {
      bf8 ae = *(const bf8*)&RESB[(cg * 16 + i) * RSTR + s2 * 32 + gq * 8];
      bf8 vp = *(const bf8*)(VP + ((size_t)(s2 * 64 + l)) * 8);
      accQ = MFMA(ae, vp, accQ);
    }
  }
  __syncthreads();   // barrier 4

  float b2v = b2[col];
#pragma unroll
  for (int rt = 0; rt < 4; ++rt)
#pragma unroll
    for (int r = 0; r < 4; ++r) {
      int row = rt * 16 + gq * 4 + r;
      float resv = (float)RESB[row * RSTR + col];
      XF[row * FSTR + col] = acc2[rt][r] + b2v + resv;
    }

  if (!last && i < 4) {
    float bvd = bvdot[i];
#pragma unroll
    for (int r = 0; r < 4; ++r) {
      int row = cg * 16 + gq * 4 + r;
      araw[(size_t)(e0 + row) * NH + i] = accQ[r] + bvd;
    }
  }
  __syncthreads();   // barrier 5

  {
    int row = tid >> 2, q = tid & 3;
    const float* fr = &XF[row * FSTR + q * 16];
    if (last) {
      float* op = efout + (size_t)(e0 + row) * DD + q * 16;
#pragma unroll
      for (int k = 0; k < 4; ++k)
        *(float4*)(op + k * 4) = *(const float4*)(fr + k * 4);
    } else {
      bf8 o0, o1;
#pragma unroll
      for (int k = 0; k < 8; ++k) { o0[k] = (__bf16)fr[k]; o1[k] = (__bf16)fr[k + 8]; }
      __bf16* op = ef16 + (size_t)(e0 + row) * DD + q * 16;
      *(bf8*)op = o0;
      *(bf8*)(op + 8) = o1;
    }
  }
}

extern "C" void kernel_launch(void* const* d_in, const int* in_sizes, int n_in,
                              void* d_out, int out_size, void* d_ws, size_t ws_size,
                              hipStream_t stream) {
  const float* node_feats = (const float*)d_in[0];
  const float* edge_feats = (const float*)d_in[1];
  const int*   edge_index = (const int*)d_in[2];
  const float* conv_w  = (const float*)d_in[3];
  const float* att_src = (const float*)d_in[4];
  const float* att_dst = (const float*)d_in[5];
  const float* edge_w  = (const float*)d_in[6];
  const float* att_edge= (const float*)d_in[7];
  const float* conv_b  = (const float*)d_in[8];
  const float* ln_g    = (const float*)d_in[9];
  const float* ln_b    = (const float*)d_in[10];
  const float* up1_w   = (const float*)d_in[11];
  const float* up1_b   = (const float*)d_in[12];
  const float* up_ln_g = (const float*)d_in[13];
  const float* up_ln_b = (const float*)d_in[14];
  const float* up2_w   = (const float*)d_in[15];
  const float* up2_b   = (const float*)d_in[16];

  const int* src = edge_index;
  const int* dst = edge_index + NE;

  float* nf = (float*)d_out;
  float* efout = nf + (size_t)NN * DD;

  float* w = (float*)d_ws;
  __bf16* xh16a = (__bf16*)w; w += (size_t)NN * DD / 2;
  __bf16* xh16b = (__bf16*)w; w += (size_t)NN * DD / 2;
  __bf16* nf16 = (__bf16*)w; w += (size_t)NN * DD / 2;
  __bf16* ef16 = (__bf16*)w; w += (size_t)NE * DD / 2;
  float* asA   = w; w += (size_t)NN * NH;
  float* adA   = w; w += (size_t)NN * NH;
  float* asB   = w; w += (size_t)NN * NH;
  float* adB   = w; w += (size_t)NN * NH;
  float* araw  = w; w += (size_t)NE * NH;
  float* vbuf  = w; w += 4 * 256;
  float* bvdot = w; w += 16;
  __bf16* W1H  = (__bf16*)w; w += (size_t)4 * 36864 / 2;
  __bf16* W2H  = (__bf16*)w; w += (size_t)4 * 12288 / 2;
  __bf16* W2VP = (__bf16*)w; w += (size_t)3 * 3072 / 2;
  __bf16* VPb  = (__bf16*)w; w += (size_t)3 * 1024 / 2;
  int* deg     = (int*)w; w += NN;
  int* offs    = (int*)w; w += NN + 2;
  int* cursor  = (int*)w; w += NN;
  int* bsum    = (int*)w; w += 128;
  int* boff    = (int*)w; w += 128;
  int2* csr_pack = (int2*)w; w += (size_t)NE * 2;

  __bf16* xh[2] = {xh16a, xh16b};
  float* as_[2] = {asA, asB};
  float* ad_[2] = {adA, adB};

  const int nb = (NN + 1023) / 1024;
  const int nzero = (NN + 255) / 256;

  // merged prep: pack W1 | pack W2 | v_all | zero deg
  k_prep<<<100 + nzero, 256, 0, stream>>>(up1_w, up2_w, edge_w, att_edge,
                                          W1H, W2H, vbuf, deg);
  k_hist<<<(NE + 255) / 256, 256, 0, stream>>>(dst, deg);
  k_scan1<<<nb, 256, 0, stream>>>(deg, offs, bsum);
  k_scan2<<<1, 64, 0, stream>>>(bsum, boff, offs, nb);
  k_scan3<<<(NN + 255) / 256, 256, 0, stream>>>(offs, boff, cursor);
  k_scatter<<<(NE + 255) / 256, 256, 0, stream>>>(src, dst, cursor, csr_pack);

  k_w2v<<<3, 384, 0, stream>>>(up2_w, up2_b, vbuf, W2VP, VPb, bvdot);
  // merged: layer-0 xh (node blocks) + pass1f (edge blocks)
  k_xh0p1<<<(NN / 4 + 1) + NE / 64, 256, 0, stream>>>(
      node_feats, edge_feats, conv_w, att_src, att_dst, vbuf,
      nf16, xh16a, asA, adA, ef16, araw);

  for (int l = 0; l < NL; ++l) {
    int last = (l == NL - 1) ? 1 : 0;
    int cur = l & 1, nxt = (l + 1) & 1;
    k_gather5<<<NN / 4 + 1, 256, 0, stream>>>(
        xh[cur], araw, csr_pack, offs, as_[cur], ad_[cur],
        conv_b + (size_t)l * DD, ln_g + (size_t)l * DD, ln_b + (size_t)l * DD,
        nf16, nf,
        last ? conv_w : (conv_w + (size_t)(l + 1) * DD * DD),
        last ? att_src : (att_src + (size_t)(l + 1) * NH * NC),
        last ? att_dst : (att_dst + (size_t)(l + 1) * NH * NC),
        xh[nxt], as_[nxt], ad_[nxt], last);
    k_edge_mlp16<<<NE / EB, 256, 0, stream>>>(
        nf16, ef16, efout, src, dst,
        W1H + (size_t)l * 36864, up1_b + (size_t)l * DIN,
        up_ln_g + (size_t)l * DIN, up_ln_b + (size_t)l * DIN,
        W2H + (size_t)l * 12288, up2_b + (size_t)l * DD,
        last ? W2VP : (W2VP + (size_t)l * 3072),
        last ? VPb : (VPb + (size_t)l * 1024),
        bvdot + (size_t)l * 4, araw, last);
  }
}

// Round 25
// 2485.925 us; speedup vs baseline: 1.0249x; 1.0152x over previous
//
#include <hip/hip_runtime.h>
#include <math.h>

#define NN 100000
#define NE 1600000
#define DD 64
#define NL 4
#define NH 4
#define NC 16
#define DIN 192
#define SLOPE 0.2f
#define EB 64
#define XSTR 200
#define FSTR 66
#define RSTR 68
#define LOG2E 1.44269504088896340736f

typedef __bf16 bf8 __attribute__((ext_vector_type(8)));
typedef __bf16 bf4 __attribute__((ext_vector_type(4)));
typedef __bf16 bf2 __attribute__((ext_vector_type(2)));
typedef float f32x4 __attribute__((ext_vector_type(4)));

__device__ __forceinline__ f32x4 MFMA(bf8 a, bf8 b, f32x4 c) {
  return __builtin_amdgcn_mfma_f32_16x16x32_bf16(a, b, c, 0, 0, 0);
}

// ---------------- merged prep: pack_w1 | pack_w2 | v_all | zero-deg ----------
__global__ void k_prep(const float* __restrict__ up1_w, const float* __restrict__ up2_w,
                       const float* __restrict__ ew_all, const float* __restrict__ ae_all,
                       __bf16* __restrict__ W1H, __bf16* __restrict__ W2H,
                       float* __restrict__ vbuf, int* __restrict__ deg) {
  int bid = blockIdx.x;
  int tid = threadIdx.x;
  if (bid < 72) {
    int gidx = bid * 256 + tid;
    if (gidx >= 4 * 4608) return;
    int lyr = gidx / 4608, rem = gidx % 4608;
    int lane = rem & 63, ts = rem >> 6;
    int s = ts % 6, t = ts / 6;
    const float* Wl = up1_w + (size_t)lyr * DIN * DIN;
    size_t base = (size_t)lyr * 36864 + ((size_t)(t * 6 + s) * 64 + lane) * 8;
    int k0 = s * 32 + (lane >> 4) * 8, n = t * 16 + (lane & 15);
#pragma unroll
    for (int j = 0; j < 8; ++j)
      W1H[base + j] = (__bf16)Wl[(size_t)(k0 + j) * DIN + n];
  } else if (bid < 96) {
    int gidx = (bid - 72) * 256 + tid;
    if (gidx >= 4 * 1536) return;
    int lyr = gidx / 1536, rem = gidx % 1536;
    int lane = rem & 63, ts = rem >> 6;
    int s = ts % 6, t = ts / 6;
    const float* Wl = up2_w + (size_t)lyr * DIN * DD;
    size_t base = (size_t)lyr * 12288 + ((size_t)(t * 6 + s) * 64 + lane) * 8;
    int k0 = s * 32 + (lane >> 4) * 8, n = t * 16 + (lane & 15);
#pragma unroll
    for (int j = 0; j < 8; ++j)
      W2H[base + j] = (__bf16)Wl[(size_t)(k0 + j) * DD + n];
  } else if (bid < 100) {
    int l = bid - 96;
    const float* ew = ew_all + (size_t)l * DD * DD;
    const float* ae = ae_all + (size_t)l * NH * NC;
    int d = tid >> 2, h = tid & 3;
    float s = 0.f;
#pragma unroll
    for (int c = 0; c < NC; ++c) s = fmaf(ew[d * DD + h * NC + c], ae[h * NC + c], s);
    vbuf[l * 256 + d * NH + h] = s;
  } else {
    int i = (bid - 100) * 256 + tid;
    if (i < NN) deg[i] = 0;
  }
}

// W2VP[l] = W2_l @ v_{l+1}; VP[l] = v_{l+1}; bvdot[l][h] = b2_l . v_{l+1}[:,h]
__global__ void k_w2v(const float* __restrict__ up2_w, const float* __restrict__ up2_b,
                      const float* __restrict__ vbuf, __bf16* __restrict__ W2VP,
                      __bf16* __restrict__ VP, float* __restrict__ bvdot) {
  int l = blockIdx.x;
  const float* vn = vbuf + (l + 1) * 256;
  int t = threadIdx.x;
  if (t < 384) {
    int s = t >> 6, lane = t & 63;
    int i = lane & 15, k0 = s * 32 + (lane >> 4) * 8;
    const float* W2 = up2_w + (size_t)l * DIN * DD;
    __bf16* out = W2VP + (size_t)l * 3072 + ((size_t)(s * 64 + lane)) * 8;
#pragma unroll
    for (int j = 0; j < 8; ++j) {
      float val = 0.f;
      if (i < 4)
        for (int n = 0; n < DD; ++n)
          val = fmaf(W2[(size_t)(k0 + j) * DD + n], vn[n * NH + i], val);
      out[j] = (__bf16)val;
    }
  }
  if (t < 128) {
    int s2 = t >> 6, lane = t & 63;
    int i = lane & 15, k0 = s2 * 32 + (lane >> 4) * 8;
    __bf16* out = VP + (size_t)l * 1024 + ((size_t)(s2 * 64 + lane)) * 8;
#pragma unroll
    for (int j = 0; j < 8; ++j)
      out[j] = (i < 4) ? (__bf16)vn[(k0 + j) * NH + i] : (__bf16)0.f;
  }
  if (t < 4) {
    const float* b2 = up2_b + (size_t)l * DD;
    float bv = 0.f;
    for (int n = 0; n < DD; ++n) bv = fmaf(b2[n], vn[n * NH + t], bv);
    bvdot[l * 4 + t] = bv;
  }
}

// ---------------- CSR build ----------------
__global__ void k_hist(const int* __restrict__ dst, int* __restrict__ deg) {
  int e = blockIdx.x * 256 + threadIdx.x;
  if (e < NE) atomicAdd(&deg[dst[e]], 1);
}

__global__ void k_scan1(const int* __restrict__ deg, int* __restrict__ offs,
                        int* __restrict__ bsum) {
  __shared__ int sh[256];
  int t = threadIdx.x, b = blockIdx.x;
  int i0 = b * 1024 + t * 4;
  int d0 = (i0 + 0 < NN) ? deg[i0 + 0] : 0;
  int d1 = (i0 + 1 < NN) ? deg[i0 + 1] : 0;
  int d2 = (i0 + 2 < NN) ? deg[i0 + 2] : 0;
  int d3 = (i0 + 3 < NN) ? deg[i0 + 3] : 0;
  int s4 = d0 + d1 + d2 + d3;
  sh[t] = s4;
  __syncthreads();
  int p = 0;
#pragma unroll
  for (int off = 1; off < 256; off <<= 1) {
    int v = (t >= off) ? sh[t - off] : 0;
    __syncthreads();
    sh[t] += v;
    __syncthreads();
  }
  p = sh[t] - s4;
  if (t == 255) bsum[b] = sh[255];
  if (i0 + 0 < NN) offs[i0 + 0] = p;
  if (i0 + 1 < NN) offs[i0 + 1] = p + d0;
  if (i0 + 2 < NN) offs[i0 + 2] = p + d0 + d1;
  if (i0 + 3 < NN) offs[i0 + 3] = p + d0 + d1 + d2;
}

__global__ void k_scan2(int* __restrict__ bsum, int* __restrict__ boff,
                        int* __restrict__ offs, int nb) {
  if (threadIdx.x == 0 && blockIdx.x == 0) {
    int run = 0;
    for (int k = 0; k < nb; ++k) { boff[k] = run; run += bsum[k]; }
    offs[NN] = NE;
  }
}

__global__ void k_scan3(int* __restrict__ offs, const int* __restrict__ boff,
                        int* __restrict__ cursor) {
  int i = blockIdx.x * 256 + threadIdx.x;
  if (i < NN) {
    int v = offs[i] + boff[i >> 10];
    offs[i] = v;
    cursor[i] = v;
  }
}

// packed CSR: csr_pack[pos] = (src[e], e); csr_dst[pos] = dst[e]
__global__ void k_scatter(const int* __restrict__ src, const int* __restrict__ dst,
                          int* __restrict__ cursor, int2* __restrict__ csr_pack,
                          int* __restrict__ csr_dst) {
  int e = blockIdx.x * 256 + threadIdx.x;
  if (e >= NE) return;
  int de = dst[e];
  int pos = atomicAdd(&cursor[de], 1);
  csr_pack[pos] = make_int2(src[e], e);
  csr_dst[pos] = de;
}

// ---------------- merged: layer-0 xh (node side) | pass1f in CSR order --------
__global__ void k_xh0p1(const float* __restrict__ node_feats,
                        const float* __restrict__ edge_feats,
                        const float* __restrict__ W, const float* __restrict__ as_,
                        const float* __restrict__ ad_, const float* __restrict__ v,
                        const int2* __restrict__ csr_pack,
                        __bf16* __restrict__ nf16, __bf16* __restrict__ xh16,
                        float* __restrict__ asrc, float* __restrict__ adst,
                        __bf16* __restrict__ ef16, float* __restrict__ araw) {
  int bid = blockIdx.x;
  if (bid < NN / 4 + 1) {
    int t = bid * 4 + (threadIdx.x >> 6);
    int d = threadIdx.x & 63;
    if (t >= NN) return;
    const float* x = node_feats + (size_t)t * DD;
    nf16[(size_t)t * DD + d] = (__bf16)x[d];
    float acc = 0.f;
#pragma unroll
    for (int k = 0; k < DD; ++k) acc = fmaf(x[k], W[k * DD + d], acc);
    xh16[(size_t)t * DD + d] = (__bf16)acc;
    int h = d >> 4, c = d & 15;
    float ps = acc * as_[h * NC + c];
    float pd = acc * ad_[h * NC + c];
#pragma unroll
    for (int off = 8; off >= 1; off >>= 1) {
      ps += __shfl_xor(ps, off, 64);
      pd += __shfl_xor(pd, off, 64);
    }
    if (c == 0) { asrc[t * NH + h] = ps; adst[t * NH + h] = pd; }
  } else {
    // pass1f in CSR position order: random edge_feats row read (one-time),
    // sequential ef16/araw writes
    int pos = (bid - (NN / 4 + 1)) * 64 + (threadIdx.x >> 2);
    int part = threadIdx.x & 3;
    if (pos >= NE) return;
    int e = csr_pack[pos].y;
    float ph0 = 0.f, ph1 = 0.f, ph2 = 0.f, ph3 = 0.f;
    const float4* ep = (const float4*)(edge_feats + (size_t)e * DD + part * 16);
    const float4* v4 = (const float4*)v;
    bf4 outv[4];
#pragma unroll
    for (int c4 = 0; c4 < 4; ++c4) {
      float4 x = ep[c4];
      outv[c4][0] = (__bf16)x.x; outv[c4][1] = (__bf16)x.y;
      outv[c4][2] = (__bf16)x.z; outv[c4][3] = (__bf16)x.w;
      int d0 = part * 16 + c4 * 4;
      float4 va = v4[d0], vb = v4[d0 + 1], vc = v4[d0 + 2], vd = v4[d0 + 3];
      ph0 = fmaf(x.x, va.x, fmaf(x.y, vb.x, fmaf(x.z, vc.x, fmaf(x.w, vd.x, ph0))));
      ph1 = fmaf(x.x, va.y, fmaf(x.y, vb.y, fmaf(x.z, vc.y, fmaf(x.w, vd.y, ph1))));
      ph2 = fmaf(x.x, va.z, fmaf(x.y, vb.z, fmaf(x.z, vc.z, fmaf(x.w, vd.z, ph2))));
      ph3 = fmaf(x.x, va.w, fmaf(x.y, vb.w, fmaf(x.z, vc.w, fmaf(x.w, vd.w, ph3))));
    }
    *(bf8*)&ef16[(size_t)pos * DD + part * 16] =
        (bf8){outv[0][0], outv[0][1], outv[0][2], outv[0][3],
              outv[1][0], outv[1][1], outv[1][2], outv[1][3]};
    *(bf8*)&ef16[(size_t)pos * DD + part * 16 + 8] =
        (bf8){outv[2][0], outv[2][1], outv[2][2], outv[2][3],
              outv[3][0], outv[3][1], outv[3][2], outv[3][3]};
#pragma unroll
    for (int off = 1; off <= 2; off <<= 1) {
      ph0 += __shfl_xor(ph0, off, 64);
      ph1 += __shfl_xor(ph1, off, 64);
      ph2 += __shfl_xor(ph2, off, 64);
      ph3 += __shfl_xor(ph3, off, 64);
    }
    float pe = (part == 0) ? ph0 : (part == 1) ? ph1 : (part == 2) ? ph2 : ph3;
    araw[(size_t)pos * NH + part] = pe;
  }
}

// gather v7: online softmax 4-wide; araw in CSR order (sequential float4 reads)
__global__ __launch_bounds__(256) void k_gather7(
    const __bf16* __restrict__ xh16, const float* __restrict__ araw,
    const int2* __restrict__ csr_pack, const int* __restrict__ offs,
    const float* __restrict__ asrc, const float* __restrict__ adst,
    const float* __restrict__ cb, const float* __restrict__ g,
    const float* __restrict__ bln, __bf16* __restrict__ nf16,
    float* __restrict__ nfout,
    const float* __restrict__ Wn, const float* __restrict__ asn,
    const float* __restrict__ adn, __bf16* __restrict__ xh16n,
    float* __restrict__ asrcn, float* __restrict__ adstn, int last) {
  int t = blockIdx.x * 4 + (threadIdx.x >> 6);
  int d = threadIdx.x & 63;
  if (t >= NN) return;
  int h = d >> 4;
  int o0 = offs[t], o1 = offs[t + 1];
  int deg = o1 - o0;
  float adh = adst[t * NH + h];

  float sh = asrc[t * NH + h] + adh;
  sh = ((sh > 0.f) ? sh : SLOPE * sh) * LOG2E;
  float m_run = sh;
  float wsum = 1.f;
  float acc = (float)xh16[(size_t)t * DD + d];

  int j = 0;
  for (; j + 3 < deg; j += 4) {
    int2 p0 = csr_pack[o0 + j], p1 = csr_pack[o0 + j + 1];
    int2 p2 = csr_pack[o0 + j + 2], p3 = csr_pack[o0 + j + 3];
    float ar0 = asrc[p0.x * NH + h] + adh + araw[(size_t)(o0 + j) * NH + h];
    float ar1 = asrc[p1.x * NH + h] + adh + araw[(size_t)(o0 + j + 1) * NH + h];
    float ar2 = asrc[p2.x * NH + h] + adh + araw[(size_t)(o0 + j + 2) * NH + h];
    float ar3 = asrc[p3.x * NH + h] + adh + araw[(size_t)(o0 + j + 3) * NH + h];
    ar0 = ((ar0 > 0.f) ? ar0 : SLOPE * ar0) * LOG2E;
    ar1 = ((ar1 > 0.f) ? ar1 : SLOPE * ar1) * LOG2E;
    ar2 = ((ar2 > 0.f) ? ar2 : SLOPE * ar2) * LOG2E;
    ar3 = ((ar3 > 0.f) ? ar3 : SLOPE * ar3) * LOG2E;
    float x0 = (float)xh16[(size_t)p0.x * DD + d];
    float x1 = (float)xh16[(size_t)p1.x * DD + d];
    float x2 = (float)xh16[(size_t)p2.x * DD + d];
    float x3 = (float)xh16[(size_t)p3.x * DD + d];
    float mnew = fmaxf(fmaxf(m_run, fmaxf(ar0, ar1)), fmaxf(ar2, ar3));
    float rold = exp2f(m_run - mnew);
    float w0 = exp2f(ar0 - mnew), w1 = exp2f(ar1 - mnew);
    float w2 = exp2f(ar2 - mnew), w3 = exp2f(ar3 - mnew);
    acc = fmaf(w3, x3, fmaf(w2, x2, fmaf(w1, x1, fmaf(w0, x0, acc * rold))));
    wsum = (w0 + w1) + (w2 + w3) + wsum * rold;
    m_run = mnew;
  }
  for (; j < deg; ++j) {
    int2 p = csr_pack[o0 + j];
    float ar = asrc[p.x * NH + h] + adh + araw[(size_t)(o0 + j) * NH + h];
    ar = ((ar > 0.f) ? ar : SLOPE * ar) * LOG2E;
    float xv = (float)xh16[(size_t)p.x * DD + d];
    float mnew = fmaxf(m_run, ar);
    float rold = exp2f(m_run - mnew);
    float w = exp2f(ar - mnew);
    acc = fmaf(w, xv, acc * rold);
    wsum = fmaf(w, 1.f, wsum * rold);
    m_run = mnew;
  }

  float val = acc / (wsum + 1e-16f) + cb[d];
  float m = val;
#pragma unroll
  for (int off = 32; off >= 1; off >>= 1) m += __shfl_xor(m, off, 64);
  m *= (1.f / 64.f);
  float c = val - m;
  float q = c * c;
#pragma unroll
  for (int off = 32; off >= 1; off >>= 1) q += __shfl_xor(q, off, 64);
  float rstd = 1.f / sqrtf(q * (1.f / 64.f) + 1e-5f);
  float y = c * rstd * g[d] + bln[d];
  y = fmaxf(y, 0.f);
  float out = y + (float)nf16[(size_t)t * DD + d];
  nf16[(size_t)t * DD + d] = (__bf16)out;

  if (last) {
    nfout[(size_t)t * DD + d] = out;
  } else {
    float acc2 = 0.f;
#pragma unroll 8
    for (int k = 0; k < DD; ++k) {
      float xk = __shfl(out, k, 64);
      acc2 = fmaf(xk, Wn[k * DD + d], acc2);
    }
    xh16n[(size_t)t * DD + d] = (__bf16)acc2;
    int cc = d & 15;
    float ps = acc2 * asn[h * NC + cc];
    float pd = acc2 * adn[h * NC + cc];
#pragma unroll
    for (int off = 8; off >= 1; off >>= 1) {
      ps += __shfl_xor(ps, off, 64);
      pd += __shfl_xor(pd, off, 64);
    }
    if (cc == 0) { asrcn[t * NH + h] = ps; adstn[t * NH + h] = pd; }
  }
}

// ---------------- edge MLP v18: CSR-position order (dst quasi-sequential) ----
__global__ __launch_bounds__(256, 4) void k_edge_mlp18(
    const __bf16* __restrict__ nf16, __bf16* __restrict__ ef16,
    float* __restrict__ efout,
    const int2* __restrict__ csr_pack, const int* __restrict__ csr_dst,
    const __bf16* __restrict__ W1H, const float* __restrict__ b1,
    const float* __restrict__ g, const float* __restrict__ bg,
    const __bf16* __restrict__ W2H, const float* __restrict__ b2,
    const __bf16* __restrict__ W2VP, const __bf16* __restrict__ VP,
    const float* __restrict__ bvdot, float* __restrict__ araw, int last) {
  __shared__ __bf16 XH[EB * XSTR];
  __shared__ __bf16 RESB[EB * RSTR];
  __shared__ __bf16 Pb[EB * 8];
  int tid = threadIdx.x;
  int e0 = blockIdx.x * EB;           // position base
  float* XF = (float*)XH;

  {
    int row = tid >> 2, p = tid & 3;
    int se = csr_pack[e0 + row].x;
    int de = csr_dst[e0 + row];
    const bf8* psrc = (const bf8*)(nf16 + (size_t)se * DD + p * 16);
    *(bf8*)&XH[row * XSTR + p * 16]     = psrc[0];
    *(bf8*)&XH[row * XSTR + p * 16 + 8] = psrc[1];
    const bf8* pdst = (const bf8*)(nf16 + (size_t)de * DD + p * 16);
    *(bf8*)&XH[row * XSTR + 64 + p * 16]     = pdst[0];
    *(bf8*)&XH[row * XSTR + 64 + p * 16 + 8] = pdst[1];
    const bf8* pef = (const bf8*)(ef16 + (size_t)(e0 + row) * DD + p * 16);
    bf8 ev0 = pef[0], ev1 = pef[1];
    *(bf8*)&XH[row * XSTR + 128 + p * 16]     = ev0;
    *(bf8*)&XH[row * XSTR + 128 + p * 16 + 8] = ev1;
    *(bf8*)&RESB[row * RSTR + p * 16]     = ev0;
    *(bf8*)&RESB[row * RSTR + p * 16 + 8] = ev1;
  }
  __syncthreads();

  int cg = tid >> 6, l = tid & 63;
  int gq = l >> 4, i = l & 15;
  int col = cg * 16 + i;

  f32x4 acc[4][3];
#pragma unroll
  for (int rt = 0; rt < 4; ++rt)
#pragma unroll
    for (int t = 0; t < 3; ++t) acc[rt][t] = (f32x4){0.f, 0.f, 0.f, 0.f};
  f32x4 accQ = (f32x4){0.f, 0.f, 0.f, 0.f};

#pragma unroll
  for (int s = 0; s < 6; ++s) {
    bf8 a[4];
#pragma unroll
    for (int rt = 0; rt < 4; ++rt)
      a[rt] = *(const bf8*)&XH[(rt * 16 + i) * XSTR + s * 32 + gq * 8];
#pragma unroll
    for (int t = 0; t < 3; ++t) {
      bf8 bh = *(const bf8*)(W1H + ((size_t)((cg * 3 + t) * 6 + s) * 64 + l) * 8);
#pragma unroll
      for (int rt = 0; rt < 4; ++rt) acc[rt][t] = MFMA(a[rt], bh, acc[rt][t]);
    }
  }

  float b1v[3], gv[3], bgv[3];
#pragma unroll
  for (int t = 0; t < 3; ++t) {
    int n = cg * 48 + t * 16 + i;
    b1v[t] = b1[n]; gv[t] = g[n]; bgv[t] = bg[n];
  }
#pragma unroll
  for (int rt = 0; rt < 4; ++rt)
#pragma unroll
    for (int t = 0; t < 3; ++t)
#pragma unroll
      for (int r = 0; r < 4; ++r) acc[rt][t][r] += b1v[t];

#pragma unroll
  for (int rt = 0; rt < 4; ++rt)
#pragma unroll
    for (int r = 0; r < 4; ++r) {
      float sm = 0.f, sq = 0.f;
#pragma unroll
      for (int t = 0; t < 3; ++t) { float x = acc[rt][t][r]; sm += x; sq = fmaf(x, x, sq); }
#pragma unroll
      for (int off = 1; off <= 8; off <<= 1) {
        sm += __shfl_xor(sm, off, 64);
        sq += __shfl_xor(sq, off, 64);
      }
      if (i == 0) {
        int row = rt * 16 + gq * 4 + r;
        bf2 pr; pr[0] = (__bf16)sm; pr[1] = (__bf16)sq;
        *(bf2*)&Pb[row * 8 + cg * 2] = pr;
      }
    }
  __syncthreads();   // barrier 1

  if (tid < EB) {
    bf8 pv = *(const bf8*)&Pb[tid * 8];
    float sm = (float)pv[0] + (float)pv[2] + (float)pv[4] + (float)pv[6];
    float sq = (float)pv[1] + (float)pv[3] + (float)pv[5] + (float)pv[7];
    float mean = sm * (1.f / (float)DIN);
    float var = sq * (1.f / (float)DIN) - mean * mean;
    float rstd = 1.f / sqrtf(var + 1e-5f);
    bf2 mv; mv[0] = (__bf16)mean; mv[1] = (__bf16)rstd;
    *(bf2*)&Pb[tid * 8] = mv;
  }
  __syncthreads();   // barrier 2

#pragma unroll
  for (int rt = 0; rt < 4; ++rt)
#pragma unroll
    for (int r = 0; r < 4; ++r) {
      int row = rt * 16 + gq * 4 + r;
      bf2 mv = *(const bf2*)&Pb[row * 8];
      float mean = (float)mv[0], rstd = (float)mv[1];
#pragma unroll
      for (int t = 0; t < 3; ++t) {
        float y = (acc[rt][t][r] - mean) * rstd * gv[t] + bgv[t];
        y = fmaxf(y, 0.f);
        XH[row * XSTR + cg * 48 + t * 16 + i] = (__bf16)y;
      }
    }
  __syncthreads();   // barrier 3

  f32x4 acc2[4];
#pragma unroll
  for (int rt = 0; rt < 4; ++rt) acc2[rt] = (f32x4){0.f, 0.f, 0.f, 0.f};

#pragma unroll
  for (int s = 0; s < 6; ++s) {
    bf8 a2[4];
#pragma unroll
    for (int rt = 0; rt < 4; ++rt)
      a2[rt] = *(const bf8*)&XH[(rt * 16 + i) * XSTR + s * 32 + gq * 8];
    bf8 bh = *(const bf8*)(W2H + ((size_t)(cg * 6 + s) * 64 + l) * 8);
#pragma unroll
    for (int rt = 0; rt < 4; ++rt) acc2[rt] = MFMA(a2[rt], bh, acc2[rt]);
    if (!last) {
      bf8 acg = *(const bf8*)&XH[(cg * 16 + i) * XSTR + s * 32 + gq * 8];
      bf8 wv = *(const bf8*)(W2VP + ((size_t)(s * 64 + l)) * 8);
      accQ = MFMA(acg, wv, accQ);
    }
  }
  if (!last) {
#pragma unroll
    for (int s2 = 0; s2 < 2; ++s2) {
      bf8 ae = *(const bf8*)&RESB[(cg * 16 + i) * RSTR + s2 * 32 + gq * 8];
      bf8 vp = *(const bf8*)(VP + ((size_t)(s2 * 64 + l)) * 8);
      accQ = MFMA(ae, vp, accQ);
    }
  }
  __syncthreads();   // barrier 4

  float b2v = b2[col];
#pragma unroll
  for (int rt = 0; rt < 4; ++rt)
#pragma unroll
    for (int r = 0; r < 4; ++r) {
      int row = rt * 16 + gq * 4 + r;
      float resv = (float)RESB[row * RSTR + col];
      XF[row * FSTR + col] = acc2[rt][r] + b2v + resv;
    }

  if (!last && i < 4) {
    float bvd = bvdot[i];
#pragma unroll
    for (int r = 0; r < 4; ++r) {
      int row = cg * 16 + gq * 4 + r;
      araw[(size_t)(e0 + row) * NH + i] = accQ[r] + bvd;   // sequential
    }
  }
  __syncthreads();   // barrier 5

  {
    int row = tid >> 2, q = tid & 3;
    const float* fr = &XF[row * FSTR + q * 16];
    if (last) {
      // scatter to original edge id: full 256B row -> two fully-dirty lines
      int eout = csr_pack[e0 + row].y;
      float* op = efout + (size_t)eout * DD + q * 16;
#pragma unroll
      for (int k = 0; k < 4; ++k)
        *(float4*)(op + k * 4) = *(const float4*)(fr + k * 4);
    } else {
      bf8 o0, o1;
#pragma unroll
      for (int k = 0; k < 8; ++k) { o0[k] = (__bf16)fr[k]; o1[k] = (__bf16)fr[k + 8]; }
      __bf16* op = ef16 + (size_t)(e0 + row) * DD + q * 16;
      *(bf8*)op = o0;
      *(bf8*)(op + 8) = o1;
    }
  }
}

extern "C" void kernel_launch(void* const* d_in, const int* in_sizes, int n_in,
                              void* d_out, int out_size, void* d_ws, size_t ws_size,
                              hipStream_t stream) {
  const float* node_feats = (const float*)d_in[0];
  const float* edge_feats = (const float*)d_in[1];
  const int*   edge_index = (const int*)d_in[2];
  const float* conv_w  = (const float*)d_in[3];
  const float* att_src = (const float*)d_in[4];
  const float* att_dst = (const float*)d_in[5];
  const float* edge_w  = (const float*)d_in[6];
  const float* att_edge= (const float*)d_in[7];
  const float* conv_b  = (const float*)d_in[8];
  const float* ln_g    = (const float*)d_in[9];
  const float* ln_b    = (const float*)d_in[10];
  const float* up1_w   = (const float*)d_in[11];
  const float* up1_b   = (const float*)d_in[12];
  const float* up_ln_g = (const float*)d_in[13];
  const float* up_ln_b = (const float*)d_in[14];
  const float* up2_w   = (const float*)d_in[15];
  const float* up2_b   = (const float*)d_in[16];

  const int* src = edge_index;
  const int* dst = edge_index + NE;

  float* nf = (float*)d_out;
  float* efout = nf + (size_t)NN * DD;

  float* w = (float*)d_ws;
  __bf16* xh16a = (__bf16*)w; w += (size_t)NN * DD / 2;
  __bf16* xh16b = (__bf16*)w; w += (size_t)NN * DD / 2;
  __bf16* nf16 = (__bf16*)w; w += (size_t)NN * DD / 2;
  __bf16* ef16 = (__bf16*)w; w += (size_t)NE * DD / 2;
  float* asA   = w; w += (size_t)NN * NH;
  float* adA   = w; w += (size_t)NN * NH;
  float* asB   = w; w += (size_t)NN * NH;
  float* adB   = w; w += (size_t)NN * NH;
  float* araw  = w; w += (size_t)NE * NH;
  float* vbuf  = w; w += 4 * 256;
  float* bvdot = w; w += 16;
  __bf16* W1H  = (__bf16*)w; w += (size_t)4 * 36864 / 2;
  __bf16* W2H  = (__bf16*)w; w += (size_t)4 * 12288 / 2;
  __bf16* W2VP = (__bf16*)w; w += (size_t)3 * 3072 / 2;
  __bf16* VPb  = (__bf16*)w; w += (size_t)3 * 1024 / 2;
  int* deg     = (int*)w; w += NN;
  int* offs    = (int*)w; w += NN + 2;
  int* cursor  = (int*)w; w += NN;
  int* bsum    = (int*)w; w += 128;
  int* boff    = (int*)w; w += 128;
  int* csr_dst = (int*)w; w += NE;
  w += 1;                                   // keep int2 array 8B-aligned
  int2* csr_pack = (int2*)w; w += (size_t)NE * 2;

  __bf16* xh[2] = {xh16a, xh16b};
  float* as_[2] = {asA, asB};
  float* ad_[2] = {adA, adB};

  const int nb = (NN + 1023) / 1024;
  const int nzero = (NN + 255) / 256;

  k_prep<<<100 + nzero, 256, 0, stream>>>(up1_w, up2_w, edge_w, att_edge,
                                          W1H, W2H, vbuf, deg);
  k_hist<<<(NE + 255) / 256, 256, 0, stream>>>(dst, deg);
  k_scan1<<<nb, 256, 0, stream>>>(deg, offs, bsum);
  k_scan2<<<1, 64, 0, stream>>>(bsum, boff, offs, nb);
  k_scan3<<<(NN + 255) / 256, 256, 0, stream>>>(offs, boff, cursor);
  k_scatter<<<(NE + 255) / 256, 256, 0, stream>>>(src, dst, cursor, csr_pack, csr_dst);

  k_w2v<<<3, 384, 0, stream>>>(up2_w, up2_b, vbuf, W2VP, VPb, bvdot);
  k_xh0p1<<<(NN / 4 + 1) + NE / 64, 256, 0, stream>>>(
      node_feats, edge_feats, conv_w, att_src, att_dst, vbuf, csr_pack,
      nf16, xh16a, asA, adA, ef16, araw);

  for (int l = 0; l < NL; ++l) {
    int last = (l == NL - 1) ? 1 : 0;
    int cur = l & 1, nxt = (l + 1) & 1;
    k_gather7<<<NN / 4 + 1, 256, 0, stream>>>(
        xh[cur], araw, csr_pack, offs, as_[cur], ad_[cur],
        conv_b + (size_t)l * DD, ln_g + (size_t)l * DD, ln_b + (size_t)l * DD,
        nf16, nf,
        last ? conv_w : (conv_w + (size_t)(l + 1) * DD * DD),
        last ? att_src : (att_src + (size_t)(l + 1) * NH * NC),
        last ? att_dst : (att_dst + (size_t)(l + 1) * NH * NC),
        xh[nxt], as_[nxt], ad_[nxt], last);
    k_edge_mlp18<<<NE / EB, 256, 0, stream>>>(
        nf16, ef16, efout, csr_pack, csr_dst,
        W1H + (size_t)l * 36864, up1_b + (size_t)l * DIN,
        up_ln_g + (size_t)l * DIN, up_ln_b + (size_t)l * DIN,
        W2H + (size_t)l * 12288, up2_b + (size_t)l * DD,
        last ? W2VP : (W2VP + (size_t)l * 3072),
        last ? VPb : (VPb + (size_t)l * 1024),
        bvdot + (size_t)l * 4, araw, last);
  }
}